// Round 11
// baseline (120.632 us; speedup 1.0000x reference)
//
#include <hip/hip_runtime.h>
#include <math.h>

#define NTX 3
#define NAX 2048
#define NEL 128
#define NX 256
#define NZ 512
#define NPIX (NZ*NX)

// FS / SOUND_SPEED
constexpr float DELAY_SCALE = 20000000.0f / 1540.0f;
constexpr float PITCH = 0.0003f;
constexpr float INV_PITCH = 1.0f / 0.0003f;

typedef _Float16 half2_t __attribute__((ext_vector_type(2)));

__device__ __forceinline__ void glds4(const void* g, void* l) {
  __builtin_amdgcn_global_load_lds(
      (const __attribute__((address_space(1))) void*)g,
      (__attribute__((address_space(3))) void*)l, 4, 0, 0);
}

// samp[t][el][ax] = (f16)data[t][ax][el]; 1.5 MB, L2-resident.
__global__ __launch_bounds__(256) void make_samp_k(const float* __restrict__ in,
                                                   _Float16* __restrict__ out) {
  __shared__ float tile[32][33];
  const int t = blockIdx.z;
  const int ax0 = blockIdx.x * 32;
  const int el0 = blockIdx.y * 32;
  const float* inp = in + (size_t)t * (NAX * NEL);
  _Float16* outp = out + (size_t)t * (NEL * NAX);
  const int lx = threadIdx.x;  // 0..31
  const int ly = threadIdx.y;  // 0..7
#pragma unroll
  for (int i = 0; i < 32; i += 8)
    tile[ly + i][lx] = inp[(size_t)(ax0 + ly + i) * NEL + (el0 + lx)];
  __syncthreads();
#pragma unroll
  for (int i = 0; i < 32; i += 8)
    outp[(size_t)(el0 + ly + i) * NAX + (ax0 + lx)] = (_Float16)tile[lx][ly + i];
}

// Bulk-tile LDS-staged DAS.
// Block = 256 thr (4 waves) on a 16x * 8z pixel tile (128 px, 2 thr/px with
// el-range halved). Per tx phase: stage, for every active el, a 128-sample
// fp16 window of samp[t][el][:] into LDS (one coalesced glds4 row per wave
// per round; ONE vmcnt(0)+barrier per phase), then the lerp reads are LDS
// dword reads + alignbit extraction. 1024 blocks, 34.5 KB LDS -> 4 blocks/CU.
//
// Window coverage proof (16x*8z tile): per (el,t),
//   w - base <= tx-spread (|s|*dX + c*dZ)*scale <= 5.1+8.8
//             + rx-spread (0.118*zmax + 1.118*dZ)*scale <= 76.7+9.8
//             + base slack (floor-2, even-1) 3 + fp eps  ~= 104 ; +1 interp
//   -> rel+1 <= ~105 < 128. Defensive clamp rel<=126.
__global__ __launch_bounds__(256, 4) void das_tile_k(const _Float16* __restrict__ samp,
                                                     const float* __restrict__ grid,
                                                     const float* __restrict__ probe,
                                                     const float* __restrict__ angles,
                                                     float* __restrict__ out) {
  __shared__ unsigned s_win[NEL][64];   // 32 KB: [row][dword]  (128 f16 / row)
  __shared__ short s_base[NTX][NEL];    // 768 B
  __shared__ float s_red[256];          // 1 KB
  const int tid = threadIdx.x;
  const int lane = tid & 63;
  const int wid = tid >> 6;

  const int x0 = (blockIdx.x & 15) * 16;
  const int z0 = (blockIdx.x >> 4) * 8;

  const float xlo = grid[3 * (z0 * NX + x0)];
  const float xhi = grid[3 * (z0 * NX + x0 + 15)];
  const float zlo = grid[3 * (z0 * NX) + 2];
  const float zhi = grid[3 * ((z0 + 7) * NX) + 2];

  // Per-(t,el) window bases: exact tx min + clamped-distance rx lower bound.
  for (int idx = tid; idx < NTX * NEL; idx += 256) {
    const int t = idx >> 7;
    const int el = idx & 127;
    const float a = angles[t];
    const float s = sinf(a), c = cosf(a);
    const float ex = ((float)el - 63.5f) * PITCH;
    const float mintx = fminf(xlo * s, xhi * s) + zlo * c;
    const float dxc = fmaxf(0.0f, fmaxf(xlo - ex, ex - xhi));
    const float mind = sqrtf(fmaf(dxc, dxc, zlo * zlo));
    int b = (int)floorf((mintx + mind) * DELAY_SCALE) - 2;
    b = b < 0 ? 0 : (b > NAX - 128 ? NAX - 128 : b);
    s_base[t][el] = (short)(b & ~1);
  }

  // Conservative active el range for the whole tile (deepest row aperture).
  const float hapmax = zhi * 0.5f;
  int lo = (int)floorf((xlo - hapmax) * INV_PITCH + 63.5f) - 1;
  int hi = (int)ceilf((xhi + hapmax) * INV_PITCH + 63.5f) + 1;
  lo = lo < 0 ? 0 : lo;
  hi = hi > NEL - 1 ? NEL - 1 : hi;
  const int nr = hi - lo + 1;
  __syncthreads();  // s_base ready

  // Pixel assignment: 2 threads per pixel, el-range halved.
  const int p = tid & 127;
  const int half = tid >> 7;
  const int xp = x0 + (p & 15);
  const int zp = z0 + (p >> 4);
  const int pix = zp * NX + xp;
  const float px = grid[3 * pix];
  const float pz = grid[3 * pix + 2];
  const float z2 = pz * pz;
  const float hap = pz * 0.5f;  // (z/F#)/2, F# = 1 (exact vs ref)

  const int h = (nr + 1) >> 1;
  const int rA = half * h;
  int rB = rA + h;
  rB = rB > nr ? nr : rB;

  float acc = 0.0f;
#pragma unroll 1
  for (int t = 0; t < NTX; ++t) {
    // ---- stage phase: each wave stages one el-row (64 dwords) per round ----
    for (int r = wid; r < nr; r += 4) {
      const int el = lo + r;
      const int b = s_base[t][el];
      const unsigned* src = (const unsigned*)samp +
                            (((unsigned)((t << 7) + el)) << 10) + (b >> 1);
      glds4(src + lane, (void*)&s_win[r][0]);
    }
    asm volatile("s_waitcnt vmcnt(0)" ::: "memory");
    __syncthreads();

    // ---- compute phase ----
    const float a = angles[t];
    const float wt = (px * sinf(a) + pz * cosf(a)) * DELAY_SCALE;
    for (int r = rA; r < rB; ++r) {
      const int el = lo + r;
      const float ex = ((float)el - 63.5f) * PITCH;  // == probe x (bitwise)
      const float dx = px - ex;
      const bool act = fabsf(dx) <= hap;             // exact ref mask
      const float drx = sqrtf(fmaf(dx, dx, z2)) * DELAY_SCALE;
      const float w = drx + wt;
      int i0 = (int)w;                               // trunc==floor after clamp
      i0 = i0 < 0 ? 0 : i0;
      int rel = i0 - (int)s_base[t][el];
      rel = rel < 0 ? 0 : (rel > 126 ? 126 : rel);   // defensive (proven in-range)
      const int k0 = rel >> 1;
      const int k1 = k0 + 1 > 63 ? 63 : k0 + 1;
      const unsigned d0 = s_win[r][k0];
      const unsigned d1 = s_win[r][k1];
      unsigned pd = (rel & 1) ? ((d0 >> 16) | (d1 << 16)) : d0;
      pd = act ? pd : 0u;                            // masked -> exact 0
      const float f1 = w - (float)i0;                // == w - d0f (exact)
      const half2_t wh = __builtin_bit_cast(
          half2_t, __builtin_amdgcn_cvt_pkrtz(1.0f - f1, f1));
      acc = __builtin_amdgcn_fdot2(wh, __builtin_bit_cast(half2_t, pd), acc, false);
    }
    __syncthreads();  // protect s_win before next phase's stage
  }

  s_red[tid] = acc;
  __syncthreads();
  if (tid < 128) out[pix] = s_red[tid] + s_red[tid + 128];
}

// ---- no-workspace fallback ----
__global__ __launch_bounds__(256) void das_fb_k(const float* __restrict__ data,
                                                const float* __restrict__ grid,
                                                const float* __restrict__ probe,
                                                const float* __restrict__ angles,
                                                float* __restrict__ out) {
  __shared__ float s_ex[NEL];
  __shared__ float s_part[256];
  const int tid = threadIdx.x;
  if (tid < NEL) s_ex[tid] = probe[3 * tid];
  __syncthreads();
  const int pix = blockIdx.x * 64 + (tid & 63);
  const int chunk = tid >> 6;
  const float px = grid[3 * pix + 0];
  const float pz = grid[3 * pix + 2];
  const float z2 = pz * pz;
  const float half_ap = pz * 0.5f;
  float wtx[NTX];
#pragma unroll
  for (int t = 0; t < NTX; ++t) {
    const float a = angles[t];
    wtx[t] = (px * sinf(a) + pz * cosf(a)) * DELAY_SCALE;
  }
  float acc = 0.0f;
  const int el_begin = chunk * 32;
  for (int e = 0; e < 32; ++e) {
    const int el = el_begin + e;
    const float ex = s_ex[el];
    const float dx = px - ex;
    if (fabsf(dx) > half_ap) continue;
    const float base = sqrtf(fmaf(dx, dx, z2)) * DELAY_SCALE;
#pragma unroll
    for (int t = 0; t < NTX; ++t) {
      const float w = base + wtx[t];
      int i0 = (int)w;
      i0 = i0 < 0 ? 0 : i0;
      const float* colp = data + (size_t)t * (NAX * NEL) + el;
      const float s0 = colp[(size_t)i0 * NEL];
      const float s1 = colp[(size_t)(i0 + 1) * NEL];
      const float f1 = w - (float)i0;
      acc = fmaf(1.0f - f1, s0, fmaf(f1, s1, acc));
    }
  }
  s_part[tid] = acc;
  __syncthreads();
  if (tid < 64) {
    out[pix] = s_part[tid] + s_part[tid + 64] + s_part[tid + 128] + s_part[tid + 192];
  }
}

extern "C" void kernel_launch(void* const* d_in, const int* in_sizes, int n_in,
                              void* d_out, int out_size, void* d_ws, size_t ws_size,
                              hipStream_t stream) {
  const float* data = (const float*)d_in[0];    // (1, 3, 2048, 128, 1)
  const float* grid = (const float*)d_in[1];    // (131072, 3)
  const float* probe = (const float*)d_in[2];   // (128, 3)
  const float* angles = (const float*)d_in[3];  // (3,)
  float* out = (float*)d_out;                   // (1, 512, 256)

  const size_t sbytes = (size_t)NTX * NEL * NAX * sizeof(_Float16);  // 1.5 MB
  if (ws_size >= sbytes) {
    _Float16* samp = (_Float16*)d_ws;
    dim3 tb(32, 8);
    dim3 tg(NAX / 32, NEL / 32, NTX);
    make_samp_k<<<tg, tb, 0, stream>>>(data, samp);
    das_tile_k<<<1024, 256, 0, stream>>>(samp, grid, probe, angles, out);
  } else {
    das_fb_k<<<NPIX / 64, 256, 0, stream>>>(data, grid, probe, angles, out);
  }
}